// Round 1
// baseline (1163.014 us; speedup 1.0000x reference)
//
#include <hip/hip_runtime.h>

typedef unsigned short u16;
typedef __bf16 bf16x8 __attribute__((ext_vector_type(8)));
typedef float f32x4 __attribute__((ext_vector_type(4)));

union BF8 {
    bf16x8 v;
    __bf16 e[8];
    u16 h[8];
};

typedef __attribute__((address_space(1))) void gvoid;
typedef __attribute__((address_space(3))) void lvoid;

__device__ __forceinline__ u16 f2bf(float f) {
    __bf16 h = (__bf16)f;
    return __builtin_bit_cast(u16, h);
}

// async global->LDS, 16B per lane; LDS dest must be wave-uniform-base + lane*16
__device__ __forceinline__ void gld_lds16(const void* g, void* l) {
    __builtin_amdgcn_global_load_lds((gvoid*)g, (lvoid*)l, 16, 0, 0);
}

__device__ __forceinline__ f32x4 mfma16(bf16x8 a, bf16x8 b, f32x4 c) {
    return __builtin_amdgcn_mfma_f32_16x16x32_bf16(a, b, c, 0, 0, 0);
}

// ---------------------------------------------------------------------------
// Transpose 768x768 f32 -> bf16 (dst[n][k] = src[k][n]) so GEMM B-operand is
// k-contiguous (global_load_lds staging needs contiguity, no LDS transpose).
// ---------------------------------------------------------------------------
__global__ __launch_bounds__(256) void transpose_cvt(const float* __restrict__ src,
                                                     u16* __restrict__ dst) {
    __shared__ float t[64][65];
    const int c0 = blockIdx.x * 64, r0 = blockIdx.y * 64;
    const int tid = threadIdx.x;
#pragma unroll
    for (int i = 0; i < 16; ++i) {
        int e = tid + 256 * i;
        int rr = e >> 6, cc = e & 63;
        t[rr][cc] = src[(r0 + rr) * 768 + c0 + cc];
    }
    __syncthreads();
#pragma unroll
    for (int i = 0; i < 16; ++i) {
        int e = tid + 256 * i;
        int rr = e >> 6, cc = e & 63;
        dst[(c0 + rr) * 768 + r0 + cc] = f2bf(t[cc][rr]);
    }
}

// ---------------------------------------------------------------------------
// GEMM: Out[M=65536][768] = A[65536][768] * Bt^T + bias  (Bt is [N][K] bf16)
// 128x128 tile, BK=32, 256 threads (2x2 waves, each 64x64 via 4x4 MFMA tiles).
// A_F32: A is f32 in global, staged f32 to LDS, cvt to bf16 at fragment load.
// ---------------------------------------------------------------------------
template <bool A_F32, bool OUT_F32>
__global__ __launch_bounds__(256) void gemm_kernel(const void* __restrict__ Aptr,
                                                   const u16* __restrict__ Bt,
                                                   const float* __restrict__ bias,
                                                   void* __restrict__ Out) {
    constexpr int ASMEM = A_F32 ? 16384 : 8192;
    __shared__ __attribute__((aligned(16))) char smem[ASMEM + 8192];
    float* Asf = (float*)smem;
    u16* Asb = (u16*)smem;
    u16* Bs = (u16*)(smem + ASMEM);

    const int tid = threadIdx.x;
    const int wid = tid >> 6, lane = tid & 63;
    const int quad = lane >> 4, lm = lane & 15;
    const int mbase = (wid >> 1) * 64, nbase = (wid & 1) * 64;
    const long row0 = (long)blockIdx.x * 128;
    const int n0 = blockIdx.y * 128;

    const f32x4 zero = {0.f, 0.f, 0.f, 0.f};
    f32x4 acc[4][4];
#pragma unroll
    for (int mi = 0; mi < 4; ++mi)
#pragma unroll
        for (int ni = 0; ni < 4; ++ni) acc[mi][ni] = zero;

    for (int kt = 0; kt < 24; ++kt) {
        const int k0 = kt * 32;
        if constexpr (A_F32) {
            const float* A = (const float*)Aptr;
#pragma unroll
            for (int i = 0; i < 4; ++i) {
                int chunk = tid + 256 * i;  // 1024 chunks of 16B = 128x32 f32
                int m = chunk >> 3, kc = chunk & 7;
                gld_lds16(A + (row0 + m) * 768 + k0 + kc * 4, Asf + chunk * 4);
            }
        } else {
            const u16* A = (const u16*)Aptr;
#pragma unroll
            for (int i = 0; i < 2; ++i) {
                int chunk = tid + 256 * i;  // 512 chunks = 128x32 bf16
                int m = chunk >> 2, kc = chunk & 3;
                gld_lds16(A + (row0 + m) * 768 + k0 + kc * 8, Asb + chunk * 8);
            }
        }
#pragma unroll
        for (int i = 0; i < 2; ++i) {
            int chunk = tid + 256 * i;  // 512 chunks = 128(n) x 32(k) bf16
            int n = chunk >> 2, kc = chunk & 3;
            gld_lds16(Bt + (long)(n0 + n) * 768 + k0 + kc * 8, Bs + chunk * 8);
        }
        __syncthreads();

        bf16x8 af[4], bfr[4];
#pragma unroll
        for (int mi = 0; mi < 4; ++mi) {
            int m = mbase + mi * 16 + lm;
            if constexpr (A_F32) {
                const float* p = Asf + m * 32 + quad * 8;
                f32x4 x0 = *(const f32x4*)p;
                f32x4 x1 = *(const f32x4*)(p + 4);
                BF8 u;
#pragma unroll
                for (int j = 0; j < 4; ++j) {
                    u.e[j] = (__bf16)x0[j];
                    u.e[4 + j] = (__bf16)x1[j];
                }
                af[mi] = u.v;
            } else {
                af[mi] = *(const bf16x8*)(Asb + m * 32 + quad * 8);
            }
        }
#pragma unroll
        for (int ni = 0; ni < 4; ++ni)
            bfr[ni] = *(const bf16x8*)(Bs + (nbase + ni * 16 + lm) * 32 + quad * 8);
#pragma unroll
        for (int mi = 0; mi < 4; ++mi)
#pragma unroll
            for (int ni = 0; ni < 4; ++ni)
                acc[mi][ni] = mfma16(af[mi], bfr[ni], acc[mi][ni]);
        __syncthreads();
    }

    // epilogue: C/D layout row = quad*4+r, col = lane&15
#pragma unroll
    for (int mi = 0; mi < 4; ++mi) {
        const long row = row0 + mbase + mi * 16 + quad * 4;
#pragma unroll
        for (int ni = 0; ni < 4; ++ni) {
            const int n = n0 + nbase + ni * 16 + lm;
            const float bv = bias[n];
#pragma unroll
            for (int r = 0; r < 4; ++r) {
                float v = acc[mi][ni][r] + bv;
                if constexpr (OUT_F32)
                    ((float*)Out)[(row + r) * 768 + n] = v;
                else
                    ((u16*)Out)[(row + r) * 768 + n] = f2bf(v);
            }
        }
    }
}

// ---------------------------------------------------------------------------
// Axis attention: one block per (cross-pos, batch, head). head<6: attend along
// H (cross=w); head>=6: attend along W (cross=h). Seq len 64, head dim 64.
// ---------------------------------------------------------------------------
__global__ __launch_bounds__(256) void attn_kernel(const u16* __restrict__ q,
                                                   const u16* __restrict__ k,
                                                   const u16* __restrict__ v,
                                                   u16* __restrict__ o) {
    __shared__ __attribute__((aligned(16))) u16 Qs[64 * 64];
    __shared__ __attribute__((aligned(16))) u16 Ks[64 * 64];
    __shared__ __attribute__((aligned(16))) u16 Vs[64 * 64];

    const int cross = blockIdx.x;
    const int b = blockIdx.y;
    const int head = blockIdx.z;
    const bool axis0 = head < 6;
    const int tid = threadIdx.x;
    const int wid = tid >> 6, lane = tid & 63;
    const int quad = lane >> 4, lm = lane & 15;

    const long base = (long)b * 4096 + (axis0 ? cross : cross * 64);
    const int pstride = axis0 ? 64 : 1;
    const int coloff = head * 64;

#pragma unroll
    for (int i = 0; i < 2; ++i) {
        int chunk = tid + 256 * i;  // 512 chunks = 64 pos x 64 d bf16
        int p = chunk >> 3, c = chunk & 7;
        long g = (base + (long)p * pstride) * 768 + coloff + c * 8;
        gld_lds16(q + g, Qs + chunk * 8);
        gld_lds16(k + g, Ks + chunk * 8);
        gld_lds16(v + g, Vs + chunk * 8);
    }
    __syncthreads();

    // S = Q K^T ; wave owns rows 16*wid..16*wid+15
    const f32x4 zero = {0.f, 0.f, 0.f, 0.f};
    f32x4 s[4];
#pragma unroll
    for (int nt = 0; nt < 4; ++nt) s[nt] = zero;

    bf16x8 qf[2];
#pragma unroll
    for (int kt = 0; kt < 2; ++kt)
        qf[kt] = *(const bf16x8*)(Qs + (16 * wid + lm) * 64 + kt * 32 + quad * 8);
#pragma unroll
    for (int nt = 0; nt < 4; ++nt)
#pragma unroll
        for (int kt = 0; kt < 2; ++kt) {
            bf16x8 kf = *(const bf16x8*)(Ks + (nt * 16 + lm) * 64 + kt * 32 + quad * 8);
            s[nt] = mfma16(qf[kt], kf, s[nt]);
        }

    // softmax over 64 keys; row h = 16*wid + quad*4 + r lives in quad-lanes x 4 regs
    float invl[4];
#pragma unroll
    for (int nt = 0; nt < 4; ++nt) s[nt] = s[nt] * 0.125f;  // 1/sqrt(64)
#pragma unroll
    for (int r = 0; r < 4; ++r) {
        float m = fmaxf(fmaxf(s[0][r], s[1][r]), fmaxf(s[2][r], s[3][r]));
#pragma unroll
        for (int d = 1; d < 16; d <<= 1) m = fmaxf(m, __shfl_xor(m, d));
        float l = 0.f;
#pragma unroll
        for (int nt = 0; nt < 4; ++nt) {
            float p = exp2f((s[nt][r] - m) * 1.44269504f);
            s[nt][r] = p;
            l += p;
        }
#pragma unroll
        for (int d = 1; d < 16; d <<= 1) l += __shfl_xor(l, d);
        invl[r] = 1.f / l;
    }

    // P (unnormalized, bf16) -> LDS in A-operand-friendly [h][x] layout (reuse Qs)
#pragma unroll
    for (int nt = 0; nt < 4; ++nt)
#pragma unroll
        for (int r = 0; r < 4; ++r)
            Qs[(16 * wid + quad * 4 + r) * 64 + nt * 16 + lm] = f2bf(s[nt][r]);
    __syncthreads();

    // O = P V
    f32x4 oacc[4];
#pragma unroll
    for (int nt = 0; nt < 4; ++nt) oacc[nt] = zero;
#pragma unroll
    for (int kt = 0; kt < 2; ++kt) {
        bf16x8 pf = *(const bf16x8*)(Qs + (16 * wid + lm) * 64 + kt * 32 + quad * 8);
#pragma unroll
        for (int nt = 0; nt < 4; ++nt) {
            BF8 vu;  // B-operand wants V^T-contiguity -> scalar reads (round 0)
#pragma unroll
            for (int j = 0; j < 8; ++j)
                vu.h[j] = Vs[(kt * 32 + quad * 8 + j) * 64 + nt * 16 + lm];
            oacc[nt] = mfma16(pf, vu.v, oacc[nt]);
        }
    }

#pragma unroll
    for (int nt = 0; nt < 4; ++nt)
#pragma unroll
        for (int r = 0; r < 4; ++r) {
            int p = 16 * wid + quad * 4 + r;
            long grow = base + (long)p * pstride;
            o[grow * 768 + coloff + nt * 16 + lm] = f2bf(oacc[nt][r] * invl[r]);
        }
}

// ---------------------------------------------------------------------------
// ws layout (u16 units): q | k | v | attn (each 65536*768) | 4 x 768*768 wts
// total = 407,371,776 bytes
// ---------------------------------------------------------------------------
extern "C" void kernel_launch(void* const* d_in, const int* in_sizes, int n_in,
                              void* d_out, int out_size, void* d_ws, size_t ws_size,
                              hipStream_t stream) {
    const float* queries = (const float*)d_in[0];
    const float* values = (const float*)d_in[1];
    const float* Wq = (const float*)d_in[2];
    const float* bq = (const float*)d_in[3];
    const float* Wk = (const float*)d_in[4];
    const float* bk = (const float*)d_in[5];
    const float* Wv = (const float*)d_in[6];
    const float* bv = (const float*)d_in[7];
    const float* Wo = (const float*)d_in[8];
    const float* bo = (const float*)d_in[9];

    const long MAT = 65536L * 768;
    const long WMAT = 768L * 768;
    u16* qws = (u16*)d_ws;
    u16* kws = qws + MAT;
    u16* vws = kws + MAT;
    u16* aws = vws + MAT;
    u16* wtq = aws + MAT;
    u16* wtk = wtq + WMAT;
    u16* wtv = wtk + WMAT;
    u16* wto = wtv + WMAT;

    dim3 tb(256);
    dim3 tg(12, 12);
    transpose_cvt<<<tg, tb, 0, stream>>>(Wq, wtq);
    transpose_cvt<<<tg, tb, 0, stream>>>(Wk, wtk);
    transpose_cvt<<<tg, tb, 0, stream>>>(Wv, wtv);
    transpose_cvt<<<tg, tb, 0, stream>>>(Wo, wto);

    dim3 gg(512, 6);
    gemm_kernel<true, false><<<gg, tb, 0, stream>>>(queries, wtq, bq, qws);
    gemm_kernel<true, false><<<gg, tb, 0, stream>>>(values, wtk, bk, kws);
    gemm_kernel<true, false><<<gg, tb, 0, stream>>>(values, wtv, bv, vws);

    attn_kernel<<<dim3(64, 16, 12), tb, 0, stream>>>(qws, kws, vws, aws);

    gemm_kernel<false, true><<<gg, tb, 0, stream>>>(aws, wto, bo, (float*)d_out);
}

// Round 2
// 1139.693 us; speedup vs baseline: 1.0205x; 1.0205x over previous
//
#include <hip/hip_runtime.h>

typedef unsigned short u16;
typedef __bf16 bf16x8 __attribute__((ext_vector_type(8)));
typedef float f32x4 __attribute__((ext_vector_type(4)));

union BF8 {
    bf16x8 v;
    __bf16 e[8];
    u16 h[8];
};

typedef __attribute__((address_space(1))) void gvoid;
typedef __attribute__((address_space(3))) void lvoid;

__device__ __forceinline__ u16 f2bf(float f) {
    __bf16 h = (__bf16)f;
    return __builtin_bit_cast(u16, h);
}

// async global->LDS, 16B per lane; LDS dest must be wave-uniform base + lane*16
__device__ __forceinline__ void gld_lds16(const void* g, void* l) {
    __builtin_amdgcn_global_load_lds((gvoid*)g, (lvoid*)l, 16, 0, 0);
}

__device__ __forceinline__ f32x4 mfma16(bf16x8 a, bf16x8 b, f32x4 c) {
    return __builtin_amdgcn_mfma_f32_16x16x32_bf16(a, b, c, 0, 0, 0);
}

// ---------------------------------------------------------------------------
// Transpose 768x768 f32 -> bf16 (dst[n][k] = src[k][n])
// ---------------------------------------------------------------------------
__global__ __launch_bounds__(256) void transpose_cvt(const float* __restrict__ src,
                                                     u16* __restrict__ dst) {
    __shared__ float t[64][65];
    const int c0 = blockIdx.x * 64, r0 = blockIdx.y * 64;
    const int tid = threadIdx.x;
#pragma unroll
    for (int i = 0; i < 16; ++i) {
        int e = tid + 256 * i;
        int rr = e >> 6, cc = e & 63;
        t[rr][cc] = src[(r0 + rr) * 768 + c0 + cc];
    }
    __syncthreads();
#pragma unroll
    for (int i = 0; i < 16; ++i) {
        int e = tid + 256 * i;
        int rr = e >> 6, cc = e & 63;
        dst[(c0 + rr) * 768 + r0 + cc] = f2bf(t[cc][rr]);
    }
}

// ---------------------------------------------------------------------------
// GEMM: Out[M=65536][768] = A[65536][768] * Bt^T + bias  (Bt is [N][K] bf16)
// 128x128 tile, BK=32, 256 threads. XOR-swizzled LDS (bank-conflict-free b128
// fragment reads, compatible with global_load_lds contiguous-dest rule).
// grid = (n-blocks, m-blocks) so A panels are reused by adjacent blocks.
// ---------------------------------------------------------------------------
template <bool A_F32, bool OUT_F32>
__global__ __launch_bounds__(256) void gemm_kernel(const void* __restrict__ Aptr,
                                                   const u16* __restrict__ Bt,
                                                   const float* __restrict__ bias,
                                                   void* __restrict__ Out) {
    constexpr int ASMEM = A_F32 ? 16384 : 8192;
    __shared__ __attribute__((aligned(16))) char smem[ASMEM + 8192];
    float* Asf = (float*)smem;
    u16* Asb = (u16*)smem;
    u16* Bs = (u16*)(smem + ASMEM);

    const int tid = threadIdx.x;
    const int wid = tid >> 6, lane = tid & 63;
    const int quad = lane >> 4, lm = lane & 15;
    const int mbase = (wid >> 1) * 64, nbase = (wid & 1) * 64;
    const long row0 = (long)blockIdx.y * 128;
    const int n0 = blockIdx.x * 128;

    const f32x4 zero = {0.f, 0.f, 0.f, 0.f};
    f32x4 acc[4][4];
#pragma unroll
    for (int mi = 0; mi < 4; ++mi)
#pragma unroll
        for (int ni = 0; ni < 4; ++ni) acc[mi][ni] = zero;

    for (int kt = 0; kt < 24; ++kt) {
        const int k0 = kt * 32;
        if constexpr (A_F32) {
            const float* A = (const float*)Aptr;
#pragma unroll
            for (int i = 0; i < 4; ++i) {
                int chunk = tid + 256 * i;  // 1024 chunks of 16B = 128x32 f32
                int m = chunk >> 3, s = chunk & 7;
                int kc = s ^ (m & 7);  // swizzled source column-chunk
                gld_lds16(A + (row0 + m) * 768 + k0 + kc * 4, Asf + chunk * 4);
            }
        } else {
            const u16* A = (const u16*)Aptr;
#pragma unroll
            for (int i = 0; i < 2; ++i) {
                int chunk = tid + 256 * i;  // 512 chunks = 128x32 bf16
                int m = chunk >> 2, s = chunk & 3;
                int kc = s ^ ((m >> 1) & 3);
                gld_lds16(A + (row0 + m) * 768 + k0 + kc * 8, Asb + chunk * 8);
            }
        }
#pragma unroll
        for (int i = 0; i < 2; ++i) {
            int chunk = tid + 256 * i;  // 512 chunks = 128(n) x 32(k) bf16
            int n = chunk >> 2, s = chunk & 3;
            int kc = s ^ ((n >> 1) & 3);
            gld_lds16(Bt + (long)(n0 + n) * 768 + k0 + kc * 8, Bs + chunk * 8);
        }
        __syncthreads();

        bf16x8 af[4], bfr[4];
#pragma unroll
        for (int mi = 0; mi < 4; ++mi) {
            int m = mbase + mi * 16 + lm;
            if constexpr (A_F32) {
                int c0 = m * 8 + ((quad * 2) ^ (m & 7));
                int c1 = m * 8 + ((quad * 2 + 1) ^ (m & 7));
                f32x4 x0 = *(const f32x4*)(Asf + c0 * 4);
                f32x4 x1 = *(const f32x4*)(Asf + c1 * 4);
                BF8 u;
#pragma unroll
                for (int j = 0; j < 4; ++j) {
                    u.e[j] = (__bf16)x0[j];
                    u.e[4 + j] = (__bf16)x1[j];
                }
                af[mi] = u.v;
            } else {
                int c = m * 4 + (quad ^ ((m >> 1) & 3));
                af[mi] = *(const bf16x8*)(Asb + c * 8);
            }
        }
#pragma unroll
        for (int ni = 0; ni < 4; ++ni) {
            int n = nbase + ni * 16 + lm;
            int c = n * 4 + (quad ^ ((n >> 1) & 3));
            bfr[ni] = *(const bf16x8*)(Bs + c * 8);
        }
#pragma unroll
        for (int mi = 0; mi < 4; ++mi)
#pragma unroll
            for (int ni = 0; ni < 4; ++ni)
                acc[mi][ni] = mfma16(af[mi], bfr[ni], acc[mi][ni]);
        __syncthreads();
    }

    // epilogue: C/D layout row = quad*4+r, col = lane&15
#pragma unroll
    for (int mi = 0; mi < 4; ++mi) {
        const long row = row0 + mbase + mi * 16 + quad * 4;
#pragma unroll
        for (int ni = 0; ni < 4; ++ni) {
            const int n = n0 + nbase + ni * 16 + lm;
            const float bv = bias[n];
#pragma unroll
            for (int r = 0; r < 4; ++r) {
                float v = acc[mi][ni][r] + bv;
                if constexpr (OUT_F32)
                    ((float*)Out)[(row + r) * 768 + n] = v;
                else
                    ((u16*)Out)[(row + r) * 768 + n] = f2bf(v);
            }
        }
    }
}

// ---------------------------------------------------------------------------
// Axis attention: one block per (cross-pos, batch, head). head<6: attend along
// H; head>=6: along W. Seq 64, head dim 64. Q/K/V staged swizzled; V
// transposed in LDS (padded stride 72) so PV B-fragments are single b128s.
// ---------------------------------------------------------------------------
__global__ __launch_bounds__(256) void attn_kernel(const u16* __restrict__ q,
                                                   const u16* __restrict__ k,
                                                   const u16* __restrict__ v,
                                                   u16* __restrict__ o) {
    __shared__ __attribute__((aligned(16))) u16 Qs[64 * 64];
    __shared__ __attribute__((aligned(16))) u16 Ks[64 * 64];
    __shared__ __attribute__((aligned(16))) u16 Vs[64 * 64];
    __shared__ __attribute__((aligned(16))) u16 Vt[64 * 72];  // padded stride

    const int cross = blockIdx.x;
    const int b = blockIdx.y;
    const int head = blockIdx.z;
    const bool axis0 = head < 6;
    const int tid = threadIdx.x;
    const int wid = tid >> 6, lane = tid & 63;
    const int quad = lane >> 4, lm = lane & 15;

    const long base = (long)b * 4096 + (axis0 ? cross : cross * 64);
    const int pstride = axis0 ? 64 : 1;
    const int coloff = head * 64;

    // stage Q,K,V swizzled: slot(p, c) = p*8 + (c ^ (p&7)), 16B chunks
#pragma unroll
    for (int i = 0; i < 2; ++i) {
        int chunk = tid + 256 * i;  // 512 chunks = 64 pos x 8 chunks
        int p = chunk >> 3, s = chunk & 7;
        int c = s ^ (p & 7);
        long g = (base + (long)p * pstride) * 768 + coloff + c * 8;
        gld_lds16(q + g, Qs + chunk * 8);
        gld_lds16(k + g, Ks + chunk * 8);
        gld_lds16(v + g, Vs + chunk * 8);
    }
    __syncthreads();

    // transpose V: Vs[pos][d] (swizzled) -> Vt[d][pos] (stride 72)
#pragma unroll
    for (int i = 0; i < 2; ++i) {
        int chunk = tid + 256 * i;
        int pos = chunk & 63, cc = chunk >> 6;  // cc wave-uniform
        int slot = pos * 8 + (cc ^ (pos & 7));
        BF8 vv;
        vv.v = *(const bf16x8*)(Vs + slot * 8);
#pragma unroll
        for (int j = 0; j < 8; ++j) Vt[(cc * 8 + j) * 72 + pos] = vv.h[j];
    }

    // S = Q K^T ; wave owns rows 16*wid..16*wid+15
    const f32x4 zero = {0.f, 0.f, 0.f, 0.f};
    f32x4 s[4];
#pragma unroll
    for (int nt = 0; nt < 4; ++nt) s[nt] = zero;

    bf16x8 qf[2];
#pragma unroll
    for (int kt = 0; kt < 2; ++kt) {
        int row = 16 * wid + lm;
        int slot = row * 8 + ((kt * 4 + quad) ^ (row & 7));
        qf[kt] = *(const bf16x8*)(Qs + slot * 8);
    }
#pragma unroll
    for (int nt = 0; nt < 4; ++nt)
#pragma unroll
        for (int kt = 0; kt < 2; ++kt) {
            int row = nt * 16 + lm;
            int slot = row * 8 + ((kt * 4 + quad) ^ (row & 7));
            bf16x8 kf = *(const bf16x8*)(Ks + slot * 8);
            s[nt] = mfma16(qf[kt], kf, s[nt]);
        }

    // softmax over 64 keys (rows h = 16*wid + quad*4 + r)
    float invl[4];
#pragma unroll
    for (int nt = 0; nt < 4; ++nt) s[nt] = s[nt] * 0.125f;  // 1/sqrt(64)
#pragma unroll
    for (int r = 0; r < 4; ++r) {
        float m = fmaxf(fmaxf(s[0][r], s[1][r]), fmaxf(s[2][r], s[3][r]));
#pragma unroll
        for (int d = 1; d < 16; d <<= 1) m = fmaxf(m, __shfl_xor(m, d));
        float l = 0.f;
#pragma unroll
        for (int nt = 0; nt < 4; ++nt) {
            float p = exp2f((s[nt][r] - m) * 1.44269504f);
            s[nt][r] = p;
            l += p;
        }
#pragma unroll
        for (int d = 1; d < 16; d <<= 1) l += __shfl_xor(l, d);
        invl[r] = 1.f / l;
    }

    // P (unnormalized bf16) -> Qs, same swizzled layout; wave writes only its
    // own 16 rows (the only Qs rows it reads), so no barrier needed here.
#pragma unroll
    for (int nt = 0; nt < 4; ++nt)
#pragma unroll
        for (int r = 0; r < 4; ++r) {
            int h = 16 * wid + quad * 4 + r;
            int c = nt * 2 + (lm >> 3);
            Qs[(h * 8 + (c ^ (h & 7))) * 8 + (lm & 7)] = f2bf(s[nt][r]);
        }
    __syncthreads();  // Vt ready (all waves) + P ready

    // O = P V ; B-fragment = single b128 from Vt
    f32x4 oacc[4];
#pragma unroll
    for (int nt = 0; nt < 4; ++nt) oacc[nt] = zero;
#pragma unroll
    for (int kt = 0; kt < 2; ++kt) {
        int row = 16 * wid + lm;
        int slot = row * 8 + ((kt * 4 + quad) ^ (row & 7));
        bf16x8 pf = *(const bf16x8*)(Qs + slot * 8);
#pragma unroll
        for (int nt = 0; nt < 4; ++nt) {
            bf16x8 vf = *(const bf16x8*)(Vt + (nt * 16 + lm) * 72 + kt * 32 + quad * 8);
            oacc[nt] = mfma16(pf, vf, oacc[nt]);
        }
    }

#pragma unroll
    for (int nt = 0; nt < 4; ++nt)
#pragma unroll
        for (int r = 0; r < 4; ++r) {
            int p = 16 * wid + quad * 4 + r;
            long grow = base + (long)p * pstride;
            o[grow * 768 + coloff + nt * 16 + lm] = f2bf(oacc[nt][r] * invl[r]);
        }
}

// ---------------------------------------------------------------------------
// ws layout (u16 units): q | k | v | attn (each 65536*768) | 4 x 768*768 wts
// ---------------------------------------------------------------------------
extern "C" void kernel_launch(void* const* d_in, const int* in_sizes, int n_in,
                              void* d_out, int out_size, void* d_ws, size_t ws_size,
                              hipStream_t stream) {
    const float* queries = (const float*)d_in[0];
    const float* values = (const float*)d_in[1];
    const float* Wq = (const float*)d_in[2];
    const float* bq = (const float*)d_in[3];
    const float* Wk = (const float*)d_in[4];
    const float* bk = (const float*)d_in[5];
    const float* Wv = (const float*)d_in[6];
    const float* bv = (const float*)d_in[7];
    const float* Wo = (const float*)d_in[8];
    const float* bo = (const float*)d_in[9];

    const long MAT = 65536L * 768;
    const long WMAT = 768L * 768;
    u16* qws = (u16*)d_ws;
    u16* kws = qws + MAT;
    u16* vws = kws + MAT;
    u16* aws = vws + MAT;
    u16* wtq = aws + MAT;
    u16* wtk = wtq + WMAT;
    u16* wtv = wtk + WMAT;
    u16* wto = wtv + WMAT;

    dim3 tb(256);
    dim3 tg(12, 12);
    transpose_cvt<<<tg, tb, 0, stream>>>(Wq, wtq);
    transpose_cvt<<<tg, tb, 0, stream>>>(Wk, wtk);
    transpose_cvt<<<tg, tb, 0, stream>>>(Wv, wtv);
    transpose_cvt<<<tg, tb, 0, stream>>>(Wo, wto);

    dim3 gg(6, 512);  // n-blocks minor: adjacent blocks share the A panel
    gemm_kernel<true, false><<<gg, tb, 0, stream>>>(queries, wtq, bq, qws);
    gemm_kernel<true, false><<<gg, tb, 0, stream>>>(values, wtk, bk, kws);
    gemm_kernel<true, false><<<gg, tb, 0, stream>>>(values, wtv, bv, vws);

    attn_kernel<<<dim3(64, 16, 12), tb, 0, stream>>>(qws, kws, vws, aws);

    gemm_kernel<false, true><<<gg, tb, 0, stream>>>(aws, wto, bo, (float*)d_out);
}